// Round 1
// baseline (664.720 us; speedup 1.0000x reference)
//
#include <hip/hip_runtime.h>
#include <hip/hip_bf16.h>

#define NFFT 8192
#define LOGN 13
#define NH   4096   // NFFT/2
#define D    1024
#define NSEQ 4096
#define PI_D 3.14159265358979323846

// ---------------- twiddle table: W[m] = exp(-2*pi*i*m/NFFT), m in [0, NH) ----------------
__global__ __launch_bounds__(256) void wtab_init(float2* __restrict__ wtab) {
    int m = blockIdx.x * 256 + threadIdx.x;
    if (m < NH) {
        double a = -2.0 * PI_D * (double)m / (double)NFFT;
        wtab[m] = make_float2((float)cos(a), (float)sin(a));
    }
}

// ---------------- in-LDS radix-2 FFT helpers (SoA re/im) ----------------
// Forward: Gentleman-Sande DIF, natural input -> bit-reversed output.
__device__ __forceinline__ void fft_fwd_dif(float* re, float* im,
                                            const float2* __restrict__ wtab, int tid) {
    for (int lh = LOGN - 1; lh >= 0; --lh) {
        int h = 1 << lh;
        for (int p = tid; p < NH; p += 256) {
            int j  = p & (h - 1);
            int i0 = ((p & ~(h - 1)) << 1) | j;
            int i1 = i0 + h;
            float ur = re[i0], ui = im[i0];
            float vr = re[i1], vi = im[i1];
            re[i0] = ur + vr;
            im[i0] = ui + vi;
            float2 w = wtab[j << (LOGN - 1 - lh)];   // exp(-i*pi*j/h)
            float dr = ur - vr, di = ui - vi;
            re[i1] = dr * w.x - di * w.y;
            im[i1] = dr * w.y + di * w.x;
        }
        __syncthreads();
    }
}

// Inverse: Cooley-Tukey DIT, bit-reversed input -> natural output (unnormalized).
__device__ __forceinline__ void fft_inv_dit(float* re, float* im,
                                            const float2* __restrict__ wtab, int tid) {
    for (int lh = 0; lh < LOGN; ++lh) {
        int h = 1 << lh;
        for (int p = tid; p < NH; p += 256) {
            int j  = p & (h - 1);
            int i0 = ((p & ~(h - 1)) << 1) | j;
            int i1 = i0 + h;
            float2 w = wtab[j << (LOGN - 1 - lh)];   // conj -> exp(+i*pi*j/h)
            float vr0 = re[i1], vi0 = im[i1];
            float vr = vr0 * w.x + vi0 * w.y;        // v * conj(w)
            float vi = vi0 * w.x - vr0 * w.y;
            float ur = re[i0], ui = im[i0];
            re[i0] = ur + vr;
            im[i0] = ui + vi;
            re[i1] = ur - vr;
            im[i1] = ui - vi;
        }
        __syncthreads();
    }
}

// ---------------- kernel B: t spectra, channel pairs packed as complex ----------------
// grid = 512 (one per d-pair). Output: bit-reversed packed spectrum Zt, 8192 float2 per pair.
__global__ __launch_bounds__(256) void tspec_kernel(const float* __restrict__ t,
                                                    const float2* __restrict__ wtab,
                                                    float2* __restrict__ tspec) {
    __shared__ float re[NFFT];
    __shared__ float im[NFFT];
    int tid = threadIdx.x;
    int dp  = blockIdx.x;
    int d0  = dp * 2;
    for (int n = tid; n < NFFT; n += 256) {
        float2 v = *(const float2*)(t + (size_t)n * D + d0);
        re[n] = v.x;
        im[n] = v.y;
    }
    __syncthreads();
    fft_fwd_dif(re, im, wtab, tid);
    float2* o = tspec + (size_t)dp * NFFT;
    for (int p = tid; p < NFFT; p += 256) {
        o[p] = make_float2(re[p], im[p]);
    }
}

// ---------------- kernel C: forward FFT of packed x, untangle*multiply*repack, inverse ----------------
// grid = 2048 = b(4) x dpair(512)
__global__ __launch_bounds__(256) void conv_kernel(const float* __restrict__ x,
                                                   const float2* __restrict__ wtab,
                                                   const float2* __restrict__ tspec,
                                                   float* __restrict__ out) {
    __shared__ float re[NFFT];
    __shared__ float im[NFFT];
    int tid = threadIdx.x;
    int wg  = blockIdx.x;
    int b   = wg >> 9;
    int dp  = wg & 511;
    int d0  = dp * 2;

    const float* xb = x + (size_t)b * NSEQ * D + d0;
    for (int n = tid; n < NSEQ; n += 256) {
        float2 v = *(const float2*)(xb + (size_t)n * D);
        re[n] = v.x;
        im[n] = v.y;
    }
    for (int n = NSEQ + tid; n < NFFT; n += 256) {
        re[n] = 0.f;
        im[n] = 0.f;
    }
    __syncthreads();

    fft_fwd_dif(re, im, wtab, tid);

    // Untangle packed spectra, multiply per channel, repack.
    // Position of bin k in bit-reversed storage is rev13(k). Thread owning k in [0, NH]
    // touches positions rev(k) and rev(NFFT-k) exclusively -> race-free in-place update.
    const float2* ts = tspec + (size_t)dp * NFFT;
    for (int k = tid; k <= NH; k += 256) {
        int p1 = (int)(__brev((unsigned)k) >> 19);
        int p2 = (int)(__brev((unsigned)((NFFT - k) & (NFFT - 1))) >> 19);
        float zr1 = re[p1], zi1 = im[p1];
        float zr2 = re[p2], zi2 = im[p2];
        // X0 = (Z[k] + conj(Z[N-k]))/2 ; X1 = (Z[k] - conj(Z[N-k]))/(2i)
        float x0r = 0.5f * (zr1 + zr2), x0i = 0.5f * (zi1 - zi2);
        float x1r = 0.5f * (zi1 + zi2), x1i = 0.5f * (zr2 - zr1);
        float2 w1 = ts[p1], w2 = ts[p2];
        float t0r = 0.5f * (w1.x + w2.x), t0i = 0.5f * (w1.y - w2.y);
        float t1r = 0.5f * (w1.y + w2.y), t1i = 0.5f * (w2.x - w1.x);
        // Y0 = X0*T0, Y1 = X1*T1
        float y0r = x0r * t0r - x0i * t0i, y0i = x0r * t0i + x0i * t0r;
        float y1r = x1r * t1r - x1i * t1i, y1i = x1r * t1i + x1i * t1r;
        // Y[k] = Y0 + i*Y1 ; Y[N-k] = conj(Y0) + i*conj(Y1)
        re[p1] = y0r - y1i;
        im[p1] = y0i + y1r;
        re[p2] = y0r + y1i;
        im[p2] = y1r - y0i;
    }
    __syncthreads();

    fft_inv_dit(re, im, wtab, tid);

    const float s = 1.0f / (float)NFFT;
    float* ob = out + (size_t)b * NSEQ * D + d0;
    for (int n = tid; n < NSEQ; n += 256) {
        float2 v = make_float2(re[n] * s, im[n] * s);
        *(float2*)(ob + (size_t)n * D) = v;
    }
}

extern "C" void kernel_launch(void* const* d_in, const int* in_sizes, int n_in,
                              void* d_out, int out_size, void* d_ws, size_t ws_size,
                              hipStream_t stream) {
    const float* x = (const float*)d_in[0];   // (4, 4096, 1024) f32
    const float* t = (const float*)d_in[1];   // (8192, 1024) f32
    float* out = (float*)d_out;               // (4, 4096, 1024) f32

    float2* wtab  = (float2*)d_ws;                                  // 32 KB
    float2* tspec = (float2*)((char*)d_ws + (size_t)NH * sizeof(float2)); // 32 MB

    wtab_init<<<16, 256, 0, stream>>>(wtab);
    tspec_kernel<<<512, 256, 0, stream>>>(t, wtab, tspec);
    conv_kernel<<<2048, 256, 0, stream>>>(x, wtab, tspec, out);
}

// Round 2
// 269.152 us; speedup vs baseline: 2.4697x; 2.4697x over previous
//
#include <hip/hip_runtime.h>
#include <hip/hip_bf16.h>

#define NFFT 8192
#define NH   4096
#define D    1024
#define NSEQ 4096
#define NDP  512
#define BATCH 4
#define NT   512
#define PI_D 3.14159265358979323846

__device__ __forceinline__ int SWZ(int i) { return i ^ ((i >> 4) & 15); }

__device__ __forceinline__ float2 cadd(float2 a, float2 b){ return make_float2(a.x+b.x, a.y+b.y); }
__device__ __forceinline__ float2 csub(float2 a, float2 b){ return make_float2(a.x-b.x, a.y-b.y); }
__device__ __forceinline__ float2 cmul(float2 a, float2 w){ return make_float2(a.x*w.x - a.y*w.y, a.x*w.y + a.y*w.x); }
__device__ __forceinline__ float2 cmulc(float2 a, float2 w){ return make_float2(a.x*w.x + a.y*w.y, a.y*w.x - a.x*w.y); }

// digit-reverse for stage radices (4,4,4,4,4,4,2), spans (2048,512,128,32,8,2,1)
__device__ __forceinline__ int drev(int k) {
    return ((k & 3) << 11) | (((k >> 2) & 3) << 9) | (((k >> 4) & 3) << 7) |
           (((k >> 6) & 3) << 5) | (((k >> 8) & 3) << 3) | (((k >> 10) & 3) << 1) |
           ((k >> 12) & 1);
}

// bank-friendly bijection (tid in [0,512), it in [0,8)) -> k in [0,4096)
__device__ __forceinline__ int kmap(int tid, int it) {
    return ((tid & 3) << 8) | (((tid >> 2) & 3) << 10) | (((tid >> 4) & 1) << 4) |
           (((tid >> 5) & 1) << 6) | (((tid >> 6) & 1) << 5) | (((tid >> 7) & 1) << 7) |
           ((tid >> 8) & 1) | (it << 1);
}

__global__ __launch_bounds__(256) void wtab_init(float2* __restrict__ wtab) {
    int m = blockIdx.x * 256 + threadIdx.x;   // grid 32 -> 8192 entries
    double a = -2.0 * PI_D * (double)m / (double)NFFT;
    wtab[m] = make_float2((float)cos(a), (float)sin(a));
}

template<int H>
__device__ __forceinline__ void fwd_stage(float2* z, const float2* __restrict__ wt, int tid) {
    const int s = 2048 / H;
    #pragma unroll
    for (int p = tid; p < 2048; p += NT) {
        int j  = p & (H - 1);
        int i0 = ((p & ~(H - 1)) << 2) + j;
        float2 z0 = z[SWZ(i0)];
        float2 z1 = z[SWZ(i0 + H)];
        float2 z2 = z[SWZ(i0 + 2*H)];
        float2 z3 = z[SWZ(i0 + 3*H)];
        float2 A  = cadd(z0, z2), C = csub(z0, z2);
        float2 Bq = cadd(z1, z3), Dq = csub(z1, z3);
        float2 e = make_float2(C.x + Dq.y, C.y - Dq.x);   // C - iD
        float2 f = make_float2(C.x - Dq.y, C.y + Dq.x);   // C + iD
        int tw = j * s;
        float2 w1 = wt[tw], w2 = wt[2*tw], w3 = wt[3*tw];
        z[SWZ(i0)]       = cadd(A, Bq);
        z[SWZ(i0 + H)]   = cmul(e, w1);
        z[SWZ(i0 + 2*H)] = cmul(csub(A, Bq), w2);
        z[SWZ(i0 + 3*H)] = cmul(f, w3);
    }
    __syncthreads();
}

template<int H>
__device__ __forceinline__ void inv_stage(float2* z, const float2* __restrict__ wt, int tid) {
    const int s = 2048 / H;
    #pragma unroll
    for (int p = tid; p < 2048; p += NT) {
        int j  = p & (H - 1);
        int i0 = ((p & ~(H - 1)) << 2) + j;
        float2 t0 = z[SWZ(i0)];
        float2 z1 = z[SWZ(i0 + H)];
        float2 z2 = z[SWZ(i0 + 2*H)];
        float2 z3 = z[SWZ(i0 + 3*H)];
        int tw = j * s;
        float2 w1 = wt[tw], w2 = wt[2*tw], w3 = wt[3*tw];
        float2 t1 = cmulc(z1, w1);
        float2 t2 = cmulc(z2, w2);
        float2 t3 = cmulc(z3, w3);
        float2 a = cadd(t0, t2), bb = csub(t0, t2);
        float2 c = cadd(t1, t3), d  = csub(t1, t3);
        z[SWZ(i0)]       = cadd(a, c);
        z[SWZ(i0 + 2*H)] = csub(a, c);
        z[SWZ(i0 + H)]   = make_float2(bb.x - d.y, bb.y + d.x);  // b + i d
        z[SWZ(i0 + 3*H)] = make_float2(bb.x + d.y, bb.y - d.x);  // b - i d
    }
    __syncthreads();
}

__device__ __forceinline__ void fft_fwd(float2* z, const float2* __restrict__ wt, int tid) {
    fwd_stage<2048>(z, wt, tid);
    fwd_stage<512>(z, wt, tid);
    fwd_stage<128>(z, wt, tid);
    fwd_stage<32>(z, wt, tid);
    fwd_stage<8>(z, wt, tid);
    fwd_stage<2>(z, wt, tid);
    #pragma unroll
    for (int p = tid; p < 4096; p += NT) {
        int i0 = 2 * p;
        float2 u = z[SWZ(i0)], v = z[SWZ(i0 + 1)];
        z[SWZ(i0)]     = cadd(u, v);
        z[SWZ(i0 + 1)] = csub(u, v);
    }
    __syncthreads();
}

__device__ __forceinline__ void fft_inv(float2* z, const float2* __restrict__ wt, int tid) {
    #pragma unroll
    for (int p = tid; p < 4096; p += NT) {
        int i0 = 2 * p;
        float2 u = z[SWZ(i0)], v = z[SWZ(i0 + 1)];
        z[SWZ(i0)]     = cadd(u, v);
        z[SWZ(i0 + 1)] = csub(u, v);
    }
    __syncthreads();
    inv_stage<2>(z, wt, tid);
    inv_stage<8>(z, wt, tid);
    inv_stage<32>(z, wt, tid);
    inv_stage<128>(z, wt, tid);
    inv_stage<512>(z, wt, tid);
    inv_stage<2048>(z, wt, tid);
}

// ---------- t spectra: FFT of packed channel pair, store UNTANGLED (T0,T1) per bin ----------
template<int PACKED>
__global__ __launch_bounds__(NT, 4) void tspec_kernel(const float2* __restrict__ tP,
                                                      const float* __restrict__ t,
                                                      const float2* __restrict__ wt,
                                                      float4* __restrict__ tspecU) {
    __shared__ float2 zs[NFFT];
    int tid = threadIdx.x;
    int dp  = blockIdx.x;
    if (PACKED) {
        const float2* slab = tP + (size_t)dp * NFFT;
        #pragma unroll
        for (int it = 0; it < 16; ++it) {
            int idx = tid + it * NT;
            zs[SWZ(idx)] = slab[idx];
        }
    } else {
        const float* tb = t + 2 * dp;
        #pragma unroll
        for (int it = 0; it < 16; ++it) {
            int idx = tid + it * NT;
            zs[SWZ(idx)] = *(const float2*)(tb + (size_t)idx * D);
        }
    }
    __syncthreads();
    fft_fwd(zs, wt, tid);
    float4* o = tspecU + (size_t)dp * (NH + 1);
    #pragma unroll
    for (int it = 0; it < 8; ++it) {
        int k  = kmap(tid, it);
        int p1 = drev(k);
        int p2 = drev((NFFT - k) & (NFFT - 1));
        float2 z1 = zs[SWZ(p1)], z2 = zs[SWZ(p2)];
        o[k] = make_float4(0.5f*(z1.x + z2.x), 0.5f*(z1.y - z2.y),
                           0.5f*(z1.y + z2.y), 0.5f*(z2.x - z1.x));
    }
    if (tid == 0) {
        float2 z1 = zs[SWZ(drev(NH))];
        o[NH] = make_float4(z1.x, 0.f, z1.y, 0.f);
    }
}

// ---------- conv: fwd FFT, untangle*mul, inv FFT ----------
template<int PACKED>
__global__ __launch_bounds__(NT, 4) void conv_kernel(float2* __restrict__ xP,
                                                     const float* __restrict__ x,
                                                     float* __restrict__ outp,
                                                     const float2* __restrict__ wt,
                                                     const float4* __restrict__ tspecU) {
    __shared__ float2 zs[NFFT];
    int tid = threadIdx.x;
    int dp  = blockIdx.x;
    int b   = blockIdx.y;

    float2* slab = PACKED ? (xP + ((size_t)dp * BATCH + b) * NSEQ) : nullptr;
    if (PACKED) {
        #pragma unroll
        for (int it = 0; it < 8; ++it) {
            int idx = tid + it * NT;
            zs[SWZ(idx)] = slab[idx];
        }
    } else {
        const float* xb = x + (size_t)b * NSEQ * D + 2 * dp;
        #pragma unroll
        for (int it = 0; it < 8; ++it) {
            int idx = tid + it * NT;
            zs[SWZ(idx)] = *(const float2*)(xb + (size_t)idx * D);
        }
    }
    #pragma unroll
    for (int it = 0; it < 8; ++it) {
        int idx = NSEQ + tid + it * NT;
        zs[SWZ(idx)] = make_float2(0.f, 0.f);
    }
    __syncthreads();

    fft_fwd(zs, wt, tid);

    const float4* ts = tspecU + (size_t)dp * (NH + 1);
    #pragma unroll
    for (int it = 0; it < 8; ++it) {
        int k  = kmap(tid, it);
        int p1 = drev(k);
        int p2 = drev((NFFT - k) & (NFFT - 1));
        float2 z1 = zs[SWZ(p1)], z2 = zs[SWZ(p2)];
        float4 t4 = ts[k];
        float x0r = 0.5f*(z1.x + z2.x), x0i = 0.5f*(z1.y - z2.y);
        float x1r = 0.5f*(z1.y + z2.y), x1i = 0.5f*(z2.x - z1.x);
        float y0r = x0r*t4.x - x0i*t4.y, y0i = x0r*t4.y + x0i*t4.x;
        float y1r = x1r*t4.z - x1i*t4.w, y1i = x1r*t4.w + x1i*t4.z;
        zs[SWZ(p1)] = make_float2(y0r - y1i, y0i + y1r);
        zs[SWZ(p2)] = make_float2(y0r + y1i, y1r - y0i);
    }
    if (tid == 0) {   // Nyquist bin k = NH at position drev(NH)=1, untouched by the loop
        int p1 = drev(NH);
        float2 z1 = zs[SWZ(p1)];
        float4 t4 = ts[NH];
        zs[SWZ(p1)] = make_float2(z1.x * t4.x, z1.y * t4.z);
    }
    __syncthreads();

    fft_inv(zs, wt, tid);

    const float sc = 1.0f / (float)NFFT;
    if (PACKED) {
        #pragma unroll
        for (int it = 0; it < 8; ++it) {
            int idx = tid + it * NT;
            float2 v = zs[SWZ(idx)];
            slab[idx] = make_float2(v.x * sc, v.y * sc);
        }
    } else {
        float* ob = outp + (size_t)b * NSEQ * D + 2 * dp;
        #pragma unroll
        for (int it = 0; it < 8; ++it) {
            int idx = tid + it * NT;
            float2 v = zs[SWZ(idx)];
            *(float2*)(ob + (size_t)idx * D) = make_float2(v.x * sc, v.y * sc);
        }
    }
}

// ---------- transpose/pack: (b,n,d) f32 -> (dp, b, n) float2 ----------
__global__ __launch_bounds__(256) void pack_kernel(const float* __restrict__ in,
                                                   float2* __restrict__ outp,
                                                   int Nrows, int Bsz) {
    __shared__ float tile[64][65];
    int tid = threadIdx.x;
    int n0 = blockIdx.x * 64;
    int d0 = blockIdx.y * 64;
    int b  = blockIdx.z;
    const float* ib = in + (size_t)b * Nrows * D;
    #pragma unroll
    for (int it = 0; it < 16; ++it) {
        int n_l = it * 4 + (tid >> 6);
        int d_l = tid & 63;
        tile[n_l][d_l] = ib[(size_t)(n0 + n_l) * D + d0 + d_l];
    }
    __syncthreads();
    #pragma unroll
    for (int it = 0; it < 8; ++it) {
        int flat = it * 256 + tid;
        int dp_l = flat >> 6;
        int n_l  = flat & 63;
        float2 v = make_float2(tile[n_l][2*dp_l], tile[n_l][2*dp_l + 1]);
        outp[((size_t)(d0/2 + dp_l) * Bsz + b) * (size_t)Nrows + n0 + n_l] = v;
    }
}

// ---------- unpack: (dp, b, n) float2 -> (b,n,d) f32 ----------
__global__ __launch_bounds__(256) void unpack_kernel(const float2* __restrict__ in,
                                                     float* __restrict__ outp) {
    __shared__ float tile[64][65];
    int tid = threadIdx.x;
    int n0 = blockIdx.x * 64;
    int d0 = blockIdx.y * 64;
    int b  = blockIdx.z;
    #pragma unroll
    for (int it = 0; it < 8; ++it) {
        int flat = it * 256 + tid;
        int dp_l = flat >> 6;
        int n_l  = flat & 63;
        float2 v = in[((size_t)(d0/2 + dp_l) * BATCH + b) * (size_t)NSEQ + n0 + n_l];
        tile[n_l][2*dp_l]     = v.x;
        tile[n_l][2*dp_l + 1] = v.y;
    }
    __syncthreads();
    float* ob = outp + (size_t)b * NSEQ * D;
    #pragma unroll
    for (int it = 0; it < 16; ++it) {
        int n_l = it * 4 + (tid >> 6);
        int d_l = tid & 63;
        ob[(size_t)(n0 + n_l) * D + d0 + d_l] = tile[n_l][d_l];
    }
}

extern "C" void kernel_launch(void* const* d_in, const int* in_sizes, int n_in,
                              void* d_out, int out_size, void* d_ws, size_t ws_size,
                              hipStream_t stream) {
    const float* x = (const float*)d_in[0];   // (4, 4096, 1024)
    const float* t = (const float*)d_in[1];   // (8192, 1024)
    float* outp = (float*)d_out;              // (4, 4096, 1024)

    char* ws = (char*)d_ws;
    float2* wtab   = (float2*)ws;                                   // 64 KB
    float4* tspecU = (float4*)(ws + 65536);                         // 512*4097*16 = 33,562,624 B
    const size_t OFF_REGION = 65536 + (size_t)NDP * (NH + 1) * 16;  // 33,628,160
    float2* region = (float2*)(ws + OFF_REGION);                    // xP/tP/oP: 64 MB
    const size_t need_full = OFF_REGION + (size_t)NDP * BATCH * NSEQ * sizeof(float2);

    wtab_init<<<32, 256, 0, stream>>>(wtab);

    if (ws_size >= need_full) {
        // pack t -> region (tP: dp x 8192)
        pack_kernel<<<dim3(128, 16, 1), 256, 0, stream>>>(t, region, NFFT, 1);
        tspec_kernel<1><<<NDP, NT, 0, stream>>>(region, nullptr, wtab, tspecU);
        // pack x -> region (xP: dp x b x 4096), overwrites tP (already consumed)
        pack_kernel<<<dim3(64, 16, BATCH), 256, 0, stream>>>(x, region, NSEQ, BATCH);
        conv_kernel<1><<<dim3(NDP, BATCH, 1), NT, 0, stream>>>(region, nullptr, nullptr, wtab, tspecU);
        unpack_kernel<<<dim3(64, 16, BATCH), 256, 0, stream>>>(region, outp);
    } else {
        // strided fallback (ws >= ~33.7 MB, proven by round-1)
        tspec_kernel<0><<<NDP, NT, 0, stream>>>(nullptr, t, wtab, tspecU);
        conv_kernel<0><<<dim3(NDP, BATCH, 1), NT, 0, stream>>>(nullptr, x, outp, wtab, tspecU);
    }
}